// Round 1
// baseline (2110.945 us; speedup 1.0000x reference)
//
#include <hip/hip_runtime.h>
#include <hip/hip_bf16.h>
#include <math.h>

#define B_    8
#define T_    4096
#define CD    1024          // ctx dim (LN-k axis)
#define DM    768           // d_model
#define NH    12
#define DH    64
#define NQ    256
#define INNER 768
#define NKV   1536          // 2*INNER
#define MKV   (B_*T_)       // 32768 rows
#define EPS   1e-5f
#define SCALE 0.125f        // dh^-0.5

// ---------------------------------------------------------------- q path ----
// One block per query row: LN over 768, then row @ Wq (768x768), scaled.
__global__ __launch_bounds__(256) void qproj_kernel(
    const float* __restrict__ query, const float* __restrict__ lnw,
    const float* __restrict__ lnb, const float* __restrict__ Wq,
    float* __restrict__ qp) {
  int row = blockIdx.x, tid = threadIdx.x;
  __shared__ __attribute__((aligned(16))) float qn[DM];
  __shared__ float rbuf[256];
  const float* qr = query + (size_t)row * DM;
  float v0 = qr[tid], v1 = qr[tid + 256], v2 = qr[tid + 512];
  rbuf[tid] = v0 + v1 + v2;
  __syncthreads();
  for (int o = 128; o > 0; o >>= 1) { if (tid < o) rbuf[tid] += rbuf[tid + o]; __syncthreads(); }
  float mean = rbuf[0] * (1.f / 768.f);
  __syncthreads();
  float d0 = v0 - mean, d1 = v1 - mean, d2 = v2 - mean;
  rbuf[tid] = d0 * d0 + d1 * d1 + d2 * d2;
  __syncthreads();
  for (int o = 128; o > 0; o >>= 1) { if (tid < o) rbuf[tid] += rbuf[tid + o]; __syncthreads(); }
  float var = rbuf[0] * (1.f / 768.f);
  float rs = rsqrtf(var + EPS);
  qn[tid]       = d0 * rs * lnw[tid]       + lnb[tid];
  qn[tid + 256] = d1 * rs * lnw[tid + 256] + lnb[tid + 256];
  qn[tid + 512] = d2 * rs * lnw[tid + 512] + lnb[tid + 512];
  __syncthreads();
  float a0 = 0.f, a1 = 0.f, a2 = 0.f;
  for (int k = 0; k < DM; ++k) {
    float q = qn[k];
    const float* wr = Wq + (size_t)k * INNER;
    a0 += q * wr[tid];
    a1 += q * wr[tid + 256];
    a2 += q * wr[tid + 512];
  }
  float* dst = qp + (size_t)row * INNER;
  dst[tid]       = a0 * SCALE;
  dst[tid + 256] = a1 * SCALE;
  dst[tid + 512] = a2 * SCALE;
}

// ------------------------------------------------------- LN stats for x ----
__global__ __launch_bounds__(256) void ln_stats_kernel(
    const float* __restrict__ x, float* __restrict__ mu, float* __restrict__ rsig) {
  int row = blockIdx.x, tid = threadIdx.x;
  float4 v = reinterpret_cast<const float4*>(x + (size_t)row * CD)[tid];
  float s  = v.x + v.y + v.z + v.w;
  float ss = v.x * v.x + v.y * v.y + v.z * v.z + v.w * v.w;
  #pragma unroll
  for (int o = 32; o > 0; o >>= 1) { s += __shfl_down(s, o); ss += __shfl_down(ss, o); }
  __shared__ float ws_[4], wss_[4];
  int wid = tid >> 6, lane = tid & 63;
  if (lane == 0) { ws_[wid] = s; wss_[wid] = ss; }
  __syncthreads();
  if (tid == 0) {
    float S  = ws_[0] + ws_[1] + ws_[2] + ws_[3];
    float SS = wss_[0] + wss_[1] + wss_[2] + wss_[3];
    float m  = S * (1.f / 1024.f);
    float var = SS * (1.f / 1024.f) - m * m;
    mu[row] = m;
    rsig[row] = rsqrtf(fmaxf(var, 0.f) + EPS);
  }
}

// -------------------------------------------- kv = LN(x) @ Wkv  (fp32) -----
// 128x128 tile, BK=16, 256 threads, 8x8 micro-tile.
#define BM 128
#define BN 128
#define BK 16
__global__ __launch_bounds__(256) void kv_gemm_kernel(
    const float* __restrict__ x, const float* __restrict__ Wkv,
    const float* __restrict__ lnw, const float* __restrict__ lnb,
    const float* __restrict__ mu, const float* __restrict__ rsig,
    float* __restrict__ kv) {
  __shared__ __attribute__((aligned(16))) float As[BK][BM + 4];
  __shared__ __attribute__((aligned(16))) float Bs[BK][BN + 4];
  int m0 = blockIdx.x * BM;
  int n0 = blockIdx.y * BN;
  int tid = threadIdx.x;
  int tm = tid >> 4, tn = tid & 15;
  float acc[8][8] = {};
  for (int k0 = 0; k0 < CD; k0 += BK) {
    #pragma unroll
    for (int i = 0; i < 2; ++i) {                 // stage A (LN fused)
      int idx = i * 256 + tid;
      int ar = idx >> 2;
      int ak = (idx & 3) * 4;
      int grow = m0 + ar;
      float4 xv = *reinterpret_cast<const float4*>(&x[(size_t)grow * CD + k0 + ak]);
      float m_ = mu[grow], r_ = rsig[grow];
      float4 wv = *reinterpret_cast<const float4*>(&lnw[k0 + ak]);
      float4 bv = *reinterpret_cast<const float4*>(&lnb[k0 + ak]);
      As[ak + 0][ar] = (xv.x - m_) * r_ * wv.x + bv.x;
      As[ak + 1][ar] = (xv.y - m_) * r_ * wv.y + bv.y;
      As[ak + 2][ar] = (xv.z - m_) * r_ * wv.z + bv.z;
      As[ak + 3][ar] = (xv.w - m_) * r_ * wv.w + bv.w;
    }
    #pragma unroll
    for (int i = 0; i < 2; ++i) {                 // stage B
      int idx = i * 256 + tid;
      int bk = idx >> 5;
      int bn = (idx & 31) * 4;
      *reinterpret_cast<float4*>(&Bs[bk][bn]) =
          *reinterpret_cast<const float4*>(&Wkv[(size_t)(k0 + bk) * NKV + n0 + bn]);
    }
    __syncthreads();
    #pragma unroll
    for (int kk = 0; kk < BK; ++kk) {
      float a[8], b[8];
      *reinterpret_cast<float4*>(&a[0]) = *reinterpret_cast<float4*>(&As[kk][tm * 8]);
      *reinterpret_cast<float4*>(&a[4]) = *reinterpret_cast<float4*>(&As[kk][tm * 8 + 4]);
      *reinterpret_cast<float4*>(&b[0]) = *reinterpret_cast<float4*>(&Bs[kk][tn * 8]);
      *reinterpret_cast<float4*>(&b[4]) = *reinterpret_cast<float4*>(&Bs[kk][tn * 8 + 4]);
      #pragma unroll
      for (int i = 0; i < 8; ++i)
        #pragma unroll
        for (int j = 0; j < 8; ++j)
          acc[i][j] += a[i] * b[j];
    }
    __syncthreads();
  }
  #pragma unroll
  for (int i = 0; i < 8; ++i) {
    int grow = m0 + tm * 8 + i;
    float* dst = &kv[(size_t)grow * NKV + n0 + tn * 8];
    *reinterpret_cast<float4*>(&dst[0]) = make_float4(acc[i][0], acc[i][1], acc[i][2], acc[i][3]);
    *reinterpret_cast<float4*>(&dst[4]) = make_float4(acc[i][4], acc[i][5], acc[i][6], acc[i][7]);
  }
}

// ------------------------------------------------ flash attention partial ---
// block: (qtile 0..3, kchunk 0..1, bh 0..95); 64 q-rows, 2048 keys in tiles of 64.
#define QT 64
#define KT 64
#define KCHUNK 2048
__global__ __launch_bounds__(256) void attn_kernel(
    const float* __restrict__ qp, const float* __restrict__ kv,
    float* __restrict__ pO, float* __restrict__ pM, float* __restrict__ pL) {
  int qt = blockIdx.x, kc = blockIdx.y, bh = blockIdx.z;
  int b = bh / NH, h = bh % NH;
  __shared__ __attribute__((aligned(16))) float qs[QT][DH + 4];
  __shared__ __attribute__((aligned(16))) float ks[KT][DH + 4];
  __shared__ __attribute__((aligned(16))) float vs[KT][DH + 4];
  __shared__ __attribute__((aligned(16))) float pl[QT][KT + 4];
  __shared__ float red[QT][17];
  int tid = threadIdx.x;
  int rg = tid >> 4;      // row group (4 rows)
  int cg = tid & 15;      // col group (4 j's for S / 4 d's for PV)
  #pragma unroll
  for (int i = 0; i < 4; ++i) {
    int idx = i * 256 + tid;
    int r = idx >> 4, d4 = (idx & 15) * 4;
    *reinterpret_cast<float4*>(&qs[r][d4]) =
        *reinterpret_cast<const float4*>(&qp[(size_t)(qt * QT + r) * INNER + h * DH + d4]);
  }
  float o[4][4] = {};
  float m_run[4], l_run[4];
  #pragma unroll
  for (int i = 0; i < 4; ++i) { m_run[i] = -1e30f; l_run[i] = 0.f; }
  const size_t kvbase = (size_t)b * T_ * NKV;
  for (int kt = 0; kt < KCHUNK / KT; ++kt) {
    int j0 = kc * KCHUNK + kt * KT;
    #pragma unroll
    for (int i = 0; i < 4; ++i) {                 // stage K, V
      int idx = i * 256 + tid;
      int j = idx >> 4, d4 = (idx & 15) * 4;
      size_t rowb = kvbase + (size_t)(j0 + j) * NKV + h * DH;
      *reinterpret_cast<float4*>(&ks[j][d4]) = *reinterpret_cast<const float4*>(&kv[rowb + d4]);
      *reinterpret_cast<float4*>(&vs[j][d4]) = *reinterpret_cast<const float4*>(&kv[rowb + INNER + d4]);
    }
    __syncthreads();
    float s[4][4] = {};
    #pragma unroll
    for (int d4 = 0; d4 < DH; d4 += 4) {          // S = Q K^T (q pre-scaled)
      float4 q4[4], k4[4];
      #pragma unroll
      for (int i = 0; i < 4; ++i) q4[i] = *reinterpret_cast<float4*>(&qs[rg * 4 + i][d4]);
      #pragma unroll
      for (int j = 0; j < 4; ++j) k4[j] = *reinterpret_cast<float4*>(&ks[cg * 4 + j][d4]);
      #pragma unroll
      for (int i = 0; i < 4; ++i)
        #pragma unroll
        for (int j = 0; j < 4; ++j)
          s[i][j] += q4[i].x * k4[j].x + q4[i].y * k4[j].y + q4[i].z * k4[j].z + q4[i].w * k4[j].w;
    }
    #pragma unroll
    for (int i = 0; i < 4; ++i)
      red[rg * 4 + i][cg] = fmaxf(fmaxf(s[i][0], s[i][1]), fmaxf(s[i][2], s[i][3]));
    __syncthreads();
    float m_new[4], alpha[4];
    #pragma unroll
    for (int i = 0; i < 4; ++i) {
      float mx = m_run[i];
      #pragma unroll
      for (int j = 0; j < 16; ++j) mx = fmaxf(mx, red[rg * 4 + i][j]);
      m_new[i] = mx;
      alpha[i] = __expf(m_run[i] - mx);
    }
    __syncthreads();
    #pragma unroll
    for (int i = 0; i < 4; ++i) {
      float p0 = __expf(s[i][0] - m_new[i]);
      float p1 = __expf(s[i][1] - m_new[i]);
      float p2 = __expf(s[i][2] - m_new[i]);
      float p3 = __expf(s[i][3] - m_new[i]);
      *reinterpret_cast<float4*>(&pl[rg * 4 + i][cg * 4]) = make_float4(p0, p1, p2, p3);
      red[rg * 4 + i][cg] = p0 + p1 + p2 + p3;
    }
    __syncthreads();
    #pragma unroll
    for (int i = 0; i < 4; ++i) {
      float ts = 0.f;
      #pragma unroll
      for (int j = 0; j < 16; ++j) ts += red[rg * 4 + i][j];
      l_run[i] = l_run[i] * alpha[i] + ts;
      m_run[i] = m_new[i];
      #pragma unroll
      for (int c = 0; c < 4; ++c) o[i][c] *= alpha[i];
    }
    #pragma unroll
    for (int j4 = 0; j4 < KT; j4 += 4) {          // O += P @ V
      float4 p4[4], v4[4];
      #pragma unroll
      for (int i = 0; i < 4; ++i) p4[i] = *reinterpret_cast<float4*>(&pl[rg * 4 + i][j4]);
      #pragma unroll
      for (int jj = 0; jj < 4; ++jj) v4[jj] = *reinterpret_cast<float4*>(&vs[j4 + jj][cg * 4]);
      #pragma unroll
      for (int i = 0; i < 4; ++i) {
        o[i][0] += p4[i].x * v4[0].x + p4[i].y * v4[1].x + p4[i].z * v4[2].x + p4[i].w * v4[3].x;
        o[i][1] += p4[i].x * v4[0].y + p4[i].y * v4[1].y + p4[i].z * v4[2].y + p4[i].w * v4[3].y;
        o[i][2] += p4[i].x * v4[0].z + p4[i].y * v4[1].z + p4[i].z * v4[2].z + p4[i].w * v4[3].z;
        o[i][3] += p4[i].x * v4[0].w + p4[i].y * v4[1].w + p4[i].z * v4[2].w + p4[i].w * v4[3].w;
      }
    }
    __syncthreads();
  }
  int pidx = bh * 2 + kc;
  #pragma unroll
  for (int i = 0; i < 4; ++i) {
    int r = qt * QT + rg * 4 + i;
    *reinterpret_cast<float4*>(&pO[((size_t)pidx * NQ + r) * DH + cg * 4]) =
        make_float4(o[i][0], o[i][1], o[i][2], o[i][3]);
    if (cg == 0) {
      pM[(size_t)pidx * NQ + r] = m_run[i];
      pL[(size_t)pidx * NQ + r] = l_run[i];
    }
  }
}

// ------------------------------------------------------- combine 2 chunks --
__global__ __launch_bounds__(256) void attn_combine_kernel(
    const float* __restrict__ pO, const float* __restrict__ pM,
    const float* __restrict__ pL, float* __restrict__ attn_out) {
  int qt = blockIdx.x, bh = blockIdx.y;
  int b = bh / NH, h = bh % NH;
  int tid = threadIdx.x;
  #pragma unroll
  for (int e = 0; e < 16; ++e) {
    int idx = e * 256 + tid;
    int r = idx >> 6, d = idx & 63;
    int row = qt * 64 + r;
    size_t i0 = (size_t)(bh * 2 + 0) * NQ + row;
    size_t i1 = (size_t)(bh * 2 + 1) * NQ + row;
    float m1 = pM[i0], m2 = pM[i1], l1 = pL[i0], l2 = pL[i1];
    float M = fmaxf(m1, m2);
    float w1 = __expf(m1 - M), w2 = __expf(m2 - M);
    float L = l1 * w1 + l2 * w2;
    float oo = (pO[i0 * DH + d] * w1 + pO[i1 * DH + d] * w2) / L;
    attn_out[((size_t)b * NQ + row) * INNER + h * DH + d] = oo;
  }
}

// --------------------------------------------------- out = attn @ Wout -----
__global__ __launch_bounds__(256) void out_gemm_kernel(
    const float* __restrict__ A, const float* __restrict__ Wt, float* __restrict__ C) {
  __shared__ __attribute__((aligned(16))) float As[16][68];
  __shared__ __attribute__((aligned(16))) float Bs[16][68];
  int m0 = blockIdx.x * 64, n0 = blockIdx.y * 64;
  int tid = threadIdx.x;
  int tm = tid >> 4, tn = tid & 15;
  float acc[4][4] = {};
  for (int k0 = 0; k0 < INNER; k0 += 16) {
    {
      int ar = tid >> 2, ak = (tid & 3) * 4;
      float4 v = *reinterpret_cast<const float4*>(&A[(size_t)(m0 + ar) * INNER + k0 + ak]);
      As[ak][ar] = v.x; As[ak + 1][ar] = v.y; As[ak + 2][ar] = v.z; As[ak + 3][ar] = v.w;
    }
    {
      int bk = tid >> 4, bn = (tid & 15) * 4;
      *reinterpret_cast<float4*>(&Bs[bk][bn]) =
          *reinterpret_cast<const float4*>(&Wt[(size_t)(k0 + bk) * DM + n0 + bn]);
    }
    __syncthreads();
    #pragma unroll
    for (int kk = 0; kk < 16; ++kk) {
      float4 a4 = *reinterpret_cast<float4*>(&As[kk][tm * 4]);
      float4 b4 = *reinterpret_cast<float4*>(&Bs[kk][tn * 4]);
      acc[0][0] += a4.x * b4.x; acc[0][1] += a4.x * b4.y; acc[0][2] += a4.x * b4.z; acc[0][3] += a4.x * b4.w;
      acc[1][0] += a4.y * b4.x; acc[1][1] += a4.y * b4.y; acc[1][2] += a4.y * b4.z; acc[1][3] += a4.y * b4.w;
      acc[2][0] += a4.z * b4.x; acc[2][1] += a4.z * b4.y; acc[2][2] += a4.z * b4.z; acc[2][3] += a4.z * b4.w;
      acc[3][0] += a4.w * b4.x; acc[3][1] += a4.w * b4.y; acc[3][2] += a4.w * b4.z; acc[3][3] += a4.w * b4.w;
    }
    __syncthreads();
  }
  #pragma unroll
  for (int i = 0; i < 4; ++i)
    *reinterpret_cast<float4*>(&C[(size_t)(m0 + tm * 4 + i) * DM + n0 + tn * 4]) =
        make_float4(acc[i][0], acc[i][1], acc[i][2], acc[i][3]);
}

// ---------------------------------------------------------------------------
extern "C" void kernel_launch(void* const* d_in, const int* in_sizes, int n_in,
                              void* d_out, int out_size, void* d_ws, size_t ws_size,
                              hipStream_t stream) {
  const float* x      = (const float*)d_in[0];
  const float* query  = (const float*)d_in[1];
  const float* ln_q_w = (const float*)d_in[2];
  const float* ln_q_b = (const float*)d_in[3];
  const float* ln_k_w = (const float*)d_in[4];
  const float* ln_k_b = (const float*)d_in[5];
  const float* Wq     = (const float*)d_in[6];
  const float* Wkv    = (const float*)d_in[7];
  const float* Wout   = (const float*)d_in[8];
  float* out = (float*)d_out;

  float* ws   = (float*)d_ws;
  float* mu   = ws;                              // 32768
  float* rsig = mu + MKV;                        // 32768
  float* qp   = rsig + MKV;                      // 196608
  float* kvb  = qp + (size_t)NQ * INNER;         // 50331648
  float* pO   = kvb + (size_t)MKV * NKV;         // 3145728
  float* pM   = pO + (size_t)B_ * NH * 2 * NQ * DH;   // 49152
  float* pL   = pM + (size_t)B_ * NH * 2 * NQ;        // 49152
  float* attn = pL + (size_t)B_ * NH * 2 * NQ;        // 1572864

  hipLaunchKernelGGL(qproj_kernel, dim3(NQ), dim3(256), 0, stream,
                     query, ln_q_w, ln_q_b, Wq, qp);
  hipLaunchKernelGGL(ln_stats_kernel, dim3(MKV), dim3(256), 0, stream, x, mu, rsig);
  hipLaunchKernelGGL(kv_gemm_kernel, dim3(MKV / BM, NKV / BN), dim3(256), 0, stream,
                     x, Wkv, ln_k_w, ln_k_b, mu, rsig, kvb);
  hipLaunchKernelGGL(attn_kernel, dim3(4, 2, B_ * NH), dim3(256), 0, stream,
                     qp, kvb, pO, pM, pL);
  hipLaunchKernelGGL(attn_combine_kernel, dim3(4, B_ * NH), dim3(256), 0, stream,
                     pO, pM, pL, attn);
  hipLaunchKernelGGL(out_gemm_kernel, dim3(2048 / 64, DM / 64), dim3(256), 0, stream,
                     attn, Wout, out);
}

// Round 3
// 1071.764 us; speedup vs baseline: 1.9696x; 1.9696x over previous
//
#include <hip/hip_runtime.h>
#include <hip/hip_bf16.h>
#include <math.h>

#define B_    8
#define T_    4096
#define CD    1024
#define DM    768
#define NH    12
#define DH    64
#define NQ    256
#define INNER 768
#define NKV   1536
#define MKV   (B_*T_)
#define EPS   1e-5f
#define SCALE 0.125f

typedef __attribute__((ext_vector_type(8))) short short8;
typedef __attribute__((ext_vector_type(4))) float f32x4;

__device__ __forceinline__ unsigned short f2bf(float f) {
  union { __hip_bfloat16 h; unsigned short u; } cv;
  cv.h = __float2bfloat16(f);
  return cv.u;
}
__device__ __forceinline__ float bf2f(unsigned short u) {
  return __uint_as_float(((unsigned int)u) << 16);
}

// ---------------------------------------------------------------- q path ----
__global__ __launch_bounds__(256) void qproj_kernel(
    const float* __restrict__ query, const float* __restrict__ lnw,
    const float* __restrict__ lnb, const float* __restrict__ Wq,
    float* __restrict__ qp) {
  int row = blockIdx.x, tid = threadIdx.x;
  __shared__ __attribute__((aligned(16))) float qn[DM];
  __shared__ float rbuf[256];
  const float* qr = query + (size_t)row * DM;
  float v0 = qr[tid], v1 = qr[tid + 256], v2 = qr[tid + 512];
  rbuf[tid] = v0 + v1 + v2;
  __syncthreads();
  for (int o = 128; o > 0; o >>= 1) { if (tid < o) rbuf[tid] += rbuf[tid + o]; __syncthreads(); }
  float mean = rbuf[0] * (1.f / 768.f);
  __syncthreads();
  float d0 = v0 - mean, d1 = v1 - mean, d2 = v2 - mean;
  rbuf[tid] = d0 * d0 + d1 * d1 + d2 * d2;
  __syncthreads();
  for (int o = 128; o > 0; o >>= 1) { if (tid < o) rbuf[tid] += rbuf[tid + o]; __syncthreads(); }
  float var = rbuf[0] * (1.f / 768.f);
  float rs = rsqrtf(var + EPS);
  qn[tid]       = d0 * rs * lnw[tid]       + lnb[tid];
  qn[tid + 256] = d1 * rs * lnw[tid + 256] + lnb[tid + 256];
  qn[tid + 512] = d2 * rs * lnw[tid + 512] + lnb[tid + 512];
  __syncthreads();
  float a0 = 0.f, a1 = 0.f, a2 = 0.f;
  for (int k = 0; k < DM; ++k) {
    float q = qn[k];
    const float* wr = Wq + (size_t)k * INNER;
    a0 += q * wr[tid];
    a1 += q * wr[tid + 256];
    a2 += q * wr[tid + 512];
  }
  float* dst = qp + (size_t)row * INNER;
  dst[tid]       = a0 * SCALE;
  dst[tid + 256] = a1 * SCALE;
  dst[tid + 512] = a2 * SCALE;
}

// ---------------------------- LN(x) -> bf16, fused stats + normalize -------
__global__ __launch_bounds__(256) void xnorm_kernel(
    const float* __restrict__ x, const float* __restrict__ lnw,
    const float* __restrict__ lnb, unsigned short* __restrict__ xn) {
  int row = blockIdx.x, tid = threadIdx.x;
  float4 v = reinterpret_cast<const float4*>(x + (size_t)row * CD)[tid];
  float s  = v.x + v.y + v.z + v.w;
  float ss = v.x * v.x + v.y * v.y + v.z * v.z + v.w * v.w;
  #pragma unroll
  for (int o = 32; o > 0; o >>= 1) { s += __shfl_down(s, o); ss += __shfl_down(ss, o); }
  __shared__ float sm[8];
  int wid = tid >> 6, lane = tid & 63;
  if (lane == 0) { sm[wid] = s; sm[4 + wid] = ss; }
  __syncthreads();
  float S  = sm[0] + sm[1] + sm[2] + sm[3];
  float SS = sm[4] + sm[5] + sm[6] + sm[7];
  float m  = S * (1.f / 1024.f);
  float var = SS * (1.f / 1024.f) - m * m;
  float rs = rsqrtf(fmaxf(var, 0.f) + EPS);
  float4 wv = reinterpret_cast<const float4*>(lnw)[tid];
  float4 bv = reinterpret_cast<const float4*>(lnb)[tid];
  ushort4 o4;
  o4.x = f2bf((v.x - m) * rs * wv.x + bv.x);
  o4.y = f2bf((v.y - m) * rs * wv.y + bv.y);
  o4.z = f2bf((v.z - m) * rs * wv.z + bv.z);
  o4.w = f2bf((v.w - m) * rs * wv.w + bv.w);
  reinterpret_cast<ushort4*>(xn + (size_t)row * CD)[tid] = o4;
}

// ---------------------- Wkv [1024][1536] -> WkvT bf16 [1536][1024] ---------
__global__ __launch_bounds__(256) void wkvt_kernel(
    const float* __restrict__ Wkv, unsigned short* __restrict__ wkvT) {
  __shared__ float tile[32][33];
  int k0 = blockIdx.x * 32, n0 = blockIdx.y * 32;
  int tid = threadIdx.x;
  int r = tid >> 3, c4 = (tid & 7) * 4;
  float4 v = *reinterpret_cast<const float4*>(&Wkv[(size_t)(k0 + r) * NKV + n0 + c4]);
  tile[r][c4 + 0] = v.x; tile[r][c4 + 1] = v.y; tile[r][c4 + 2] = v.z; tile[r][c4 + 3] = v.w;
  __syncthreads();
  ushort4 o4;
  o4.x = f2bf(tile[c4 + 0][r]);
  o4.y = f2bf(tile[c4 + 1][r]);
  o4.z = f2bf(tile[c4 + 2][r]);
  o4.w = f2bf(tile[c4 + 3][r]);
  *reinterpret_cast<ushort4*>(&wkvT[(size_t)(n0 + r) * CD + k0 + c4]) = o4;
}

// --------------------- kv = xn @ WkvT^T  (bf16 MFMA, fp32 acc) -------------
// 128x128 tile, BK=64, 4 waves (2x2), 4x4 fragments of 16x16x32 per wave.
// LDS linear dest for global_load_lds; source pre-swizzled (slot ^= row&7),
// ds_read applies the same XOR -> conflict-free (2-way max, free).
#define GBM 128
#define GBN 128
#define GBK 64
__global__ __launch_bounds__(256) void kv_mfma_kernel(
    const unsigned short* __restrict__ xn, const unsigned short* __restrict__ wkvT,
    unsigned short* __restrict__ kvb) {
  __shared__ __attribute__((aligned(16))) unsigned short As[GBM * GBK];  // 16 KB
  __shared__ __attribute__((aligned(16))) unsigned short Bs[GBN * GBK];  // 16 KB
  int tid = threadIdx.x;
  int w = tid >> 6, lane = tid & 63;

  // XCD-aware swizzle (3072 blocks, %8==0 -> simple form bijective)
  int bid = blockIdx.x;
  int sw = (bid & 7) * (3072 / 8) + (bid >> 3);
  int mt = sw / (NKV / GBN), nt = sw % (NKV / GBN);
  int m0 = mt * GBM, n0 = nt * GBN;

  // staging geometry: per wave 4 insts for A, 4 for B; inst i covers LDS
  // bytes [w*4096 + i*1024 + lane*16, +16)
  int srow[4], skoff[4];
  #pragma unroll
  for (int i = 0; i < 4; ++i) {
    int L = w * 4096 + i * 1024 + lane * 16;
    int row = L >> 7;
    int slot = (L >> 4) & 7;
    srow[i] = row;
    skoff[i] = ((slot ^ (row & 7)) << 3);  // element offset within BK
  }

  f32x4 acc[4][4];
  #pragma unroll
  for (int m = 0; m < 4; ++m)
    #pragma unroll
    for (int n = 0; n < 4; ++n) acc[m][n] = (f32x4){0.f, 0.f, 0.f, 0.f};

  int wr = w >> 1, wc = w & 1;
  int l15 = lane & 15, l4 = lane >> 4;

  for (int t = 0; t < CD / GBK; ++t) {
    int k0 = t * GBK;
    #pragma unroll
    for (int i = 0; i < 4; ++i) {
      __builtin_amdgcn_global_load_lds(
          (const __attribute__((address_space(1))) void*)(xn + (size_t)(m0 + srow[i]) * CD + k0 + skoff[i]),
          (__attribute__((address_space(3))) void*)(As + w * 2048 + i * 512 + lane * 8),
          16, 0, 0);
    }
    #pragma unroll
    for (int i = 0; i < 4; ++i) {
      __builtin_amdgcn_global_load_lds(
          (const __attribute__((address_space(1))) void*)(wkvT + (size_t)(n0 + srow[i]) * CD + k0 + skoff[i]),
          (__attribute__((address_space(3))) void*)(Bs + w * 2048 + i * 512 + lane * 8),
          16, 0, 0);
    }
    __syncthreads();   // vmcnt(0) drain + barrier
    #pragma unroll
    for (int kh = 0; kh < 2; ++kh) {
      short8 af[4], bf[4];
      #pragma unroll
      for (int m = 0; m < 4; ++m) {
        int row = wr * 64 + m * 16 + l15;
        int byte = row * 128 + (((l4 + 4 * kh) ^ (row & 7)) << 4);
        af[m] = *reinterpret_cast<const short8*>(reinterpret_cast<const char*>(As) + byte);
      }
      #pragma unroll
      for (int n = 0; n < 4; ++n) {
        int row = wc * 64 + n * 16 + l15;
        int byte = row * 128 + (((l4 + 4 * kh) ^ (row & 7)) << 4);
        bf[n] = *reinterpret_cast<const short8*>(reinterpret_cast<const char*>(Bs) + byte);
      }
      #pragma unroll
      for (int m = 0; m < 4; ++m)
        #pragma unroll
        for (int n = 0; n < 4; ++n)
          acc[m][n] = __builtin_amdgcn_mfma_f32_16x16x32_bf16(af[m], bf[n], acc[m][n], 0, 0, 0);
    }
    __syncthreads();   // reads done before next stage overwrites
  }

  // C-write: col = lane&15, row = (lane>>4)*4 + reg  (m89-verified layout)
  #pragma unroll
  for (int m = 0; m < 4; ++m) {
    int grow = m0 + wr * 64 + m * 16 + l4 * 4;
    #pragma unroll
    for (int n = 0; n < 4; ++n) {
      int gcol = n0 + wc * 64 + n * 16 + l15;
      #pragma unroll
      for (int r = 0; r < 4; ++r)
        kvb[(size_t)(grow + r) * NKV + gcol] = f2bf(acc[m][n][r]);
    }
  }
}

// ------------------------------------------------ flash attention partial ---
#define QT 64
#define KT 64
#define KCHUNK 2048
__global__ __launch_bounds__(256) void attn_kernel(
    const float* __restrict__ qp, const unsigned short* __restrict__ kvb,
    float* __restrict__ pO, float* __restrict__ pM, float* __restrict__ pL) {
  int qt = blockIdx.x, kc = blockIdx.y, bh = blockIdx.z;
  int b = bh / NH, h = bh % NH;
  __shared__ __attribute__((aligned(16))) float qs[QT][DH + 4];
  __shared__ __attribute__((aligned(16))) float ks[KT][DH + 4];
  __shared__ __attribute__((aligned(16))) float vs[KT][DH + 4];
  __shared__ __attribute__((aligned(16))) float pl[QT][KT + 4];
  __shared__ float red[QT][17];
  int tid = threadIdx.x;
  int rg = tid >> 4;
  int cg = tid & 15;
  #pragma unroll
  for (int i = 0; i < 4; ++i) {
    int idx = i * 256 + tid;
    int r = idx >> 4, d4 = (idx & 15) * 4;
    *reinterpret_cast<float4*>(&qs[r][d4]) =
        *reinterpret_cast<const float4*>(&qp[(size_t)(qt * QT + r) * INNER + h * DH + d4]);
  }
  float o[4][4] = {};
  float m_run[4], l_run[4];
  #pragma unroll
  for (int i = 0; i < 4; ++i) { m_run[i] = -1e30f; l_run[i] = 0.f; }
  const size_t kvbase = (size_t)b * T_ * NKV;
  for (int kt = 0; kt < KCHUNK / KT; ++kt) {
    int j0 = kc * KCHUNK + kt * KT;
    #pragma unroll
    for (int i = 0; i < 4; ++i) {
      int idx = i * 256 + tid;
      int j = idx >> 4, d4 = (idx & 15) * 4;
      size_t rowb = kvbase + (size_t)(j0 + j) * NKV + h * DH;
      ushort4 ku = *reinterpret_cast<const ushort4*>(&kvb[rowb + d4]);
      ushort4 vu = *reinterpret_cast<const ushort4*>(&kvb[rowb + INNER + d4]);
      ks[j][d4 + 0] = bf2f(ku.x); ks[j][d4 + 1] = bf2f(ku.y);
      ks[j][d4 + 2] = bf2f(ku.z); ks[j][d4 + 3] = bf2f(ku.w);
      vs[j][d4 + 0] = bf2f(vu.x); vs[j][d4 + 1] = bf2f(vu.y);
      vs[j][d4 + 2] = bf2f(vu.z); vs[j][d4 + 3] = bf2f(vu.w);
    }
    __syncthreads();
    float s[4][4] = {};
    #pragma unroll
    for (int d4 = 0; d4 < DH; d4 += 4) {
      float4 q4[4], k4[4];
      #pragma unroll
      for (int i = 0; i < 4; ++i) q4[i] = *reinterpret_cast<float4*>(&qs[rg * 4 + i][d4]);
      #pragma unroll
      for (int j = 0; j < 4; ++j) k4[j] = *reinterpret_cast<float4*>(&ks[cg * 4 + j][d4]);
      #pragma unroll
      for (int i = 0; i < 4; ++i)
        #pragma unroll
        for (int j = 0; j < 4; ++j)
          s[i][j] += q4[i].x * k4[j].x + q4[i].y * k4[j].y + q4[i].z * k4[j].z + q4[i].w * k4[j].w;
    }
    #pragma unroll
    for (int i = 0; i < 4; ++i)
      red[rg * 4 + i][cg] = fmaxf(fmaxf(s[i][0], s[i][1]), fmaxf(s[i][2], s[i][3]));
    __syncthreads();
    float m_new[4], alpha[4];
    #pragma unroll
    for (int i = 0; i < 4; ++i) {
      float mx = m_run[i];
      #pragma unroll
      for (int j = 0; j < 16; ++j) mx = fmaxf(mx, red[rg * 4 + i][j]);
      m_new[i] = mx;
      alpha[i] = __expf(m_run[i] - mx);
    }
    __syncthreads();
    #pragma unroll
    for (int i = 0; i < 4; ++i) {
      float p0 = __expf(s[i][0] - m_new[i]);
      float p1 = __expf(s[i][1] - m_new[i]);
      float p2 = __expf(s[i][2] - m_new[i]);
      float p3 = __expf(s[i][3] - m_new[i]);
      *reinterpret_cast<float4*>(&pl[rg * 4 + i][cg * 4]) = make_float4(p0, p1, p2, p3);
      red[rg * 4 + i][cg] = p0 + p1 + p2 + p3;
    }
    __syncthreads();
    #pragma unroll
    for (int i = 0; i < 4; ++i) {
      float ts = 0.f;
      #pragma unroll
      for (int j = 0; j < 16; ++j) ts += red[rg * 4 + i][j];
      l_run[i] = l_run[i] * alpha[i] + ts;
      m_run[i] = m_new[i];
      #pragma unroll
      for (int c = 0; c < 4; ++c) o[i][c] *= alpha[i];
    }
    #pragma unroll
    for (int j4 = 0; j4 < KT; j4 += 4) {
      float4 p4[4], v4[4];
      #pragma unroll
      for (int i = 0; i < 4; ++i) p4[i] = *reinterpret_cast<float4*>(&pl[rg * 4 + i][j4]);
      #pragma unroll
      for (int jj = 0; jj < 4; ++jj) v4[jj] = *reinterpret_cast<float4*>(&vs[j4 + jj][cg * 4]);
      #pragma unroll
      for (int i = 0; i < 4; ++i) {
        o[i][0] += p4[i].x * v4[0].x + p4[i].y * v4[1].x + p4[i].z * v4[2].x + p4[i].w * v4[3].x;
        o[i][1] += p4[i].x * v4[0].y + p4[i].y * v4[1].y + p4[i].z * v4[2].y + p4[i].w * v4[3].y;
        o[i][2] += p4[i].x * v4[0].z + p4[i].y * v4[1].z + p4[i].z * v4[2].z + p4[i].w * v4[3].z;
        o[i][3] += p4[i].x * v4[0].w + p4[i].y * v4[1].w + p4[i].z * v4[2].w + p4[i].w * v4[3].w;
      }
    }
    __syncthreads();
  }
  int pidx = bh * 2 + kc;
  #pragma unroll
  for (int i = 0; i < 4; ++i) {
    int r = qt * QT + rg * 4 + i;
    *reinterpret_cast<float4*>(&pO[((size_t)pidx * NQ + r) * DH + cg * 4]) =
        make_float4(o[i][0], o[i][1], o[i][2], o[i][3]);
    if (cg == 0) {
      pM[(size_t)pidx * NQ + r] = m_run[i];
      pL[(size_t)pidx * NQ + r] = l_run[i];
    }
  }
}

// ------------------------------------------------------- combine 2 chunks --
__global__ __launch_bounds__(256) void attn_combine_kernel(
    const float* __restrict__ pO, const float* __restrict__ pM,
    const float* __restrict__ pL, float* __restrict__ attn_out) {
  int qt = blockIdx.x, bh = blockIdx.y;
  int b = bh / NH, h = bh % NH;
  int tid = threadIdx.x;
  #pragma unroll
  for (int e = 0; e < 16; ++e) {
    int idx = e * 256 + tid;
    int r = idx >> 6, d = idx & 63;
    int row = qt * 64 + r;
    size_t i0 = (size_t)(bh * 2 + 0) * NQ + row;
    size_t i1 = (size_t)(bh * 2 + 1) * NQ + row;
    float m1 = pM[i0], m2 = pM[i1], l1 = pL[i0], l2 = pL[i1];
    float M = fmaxf(m1, m2);
    float w1 = __expf(m1 - M), w2 = __expf(m2 - M);
    float L = l1 * w1 + l2 * w2;
    float oo = (pO[i0 * DH + d] * w1 + pO[i1 * DH + d] * w2) / L;
    attn_out[((size_t)b * NQ + row) * INNER + h * DH + d] = oo;
  }
}

// --------------------------------------------------- out = attn @ Wout -----
__global__ __launch_bounds__(256) void out_gemm_kernel(
    const float* __restrict__ A, const float* __restrict__ Wt, float* __restrict__ C) {
  __shared__ __attribute__((aligned(16))) float As[16][68];
  __shared__ __attribute__((aligned(16))) float Bs[16][68];
  int m0 = blockIdx.x * 64, n0 = blockIdx.y * 64;
  int tid = threadIdx.x;
  int tm = tid >> 4, tn = tid & 15;
  float acc[4][4] = {};
  for (int k0 = 0; k0 < INNER; k0 += 16) {
    {
      int ar = tid >> 2, ak = (tid & 3) * 4;
      float4 v = *reinterpret_cast<const float4*>(&A[(size_t)(m0 + ar) * INNER + k0 + ak]);
      As[ak][ar] = v.x; As[ak + 1][ar] = v.y; As[ak + 2][ar] = v.z; As[ak + 3][ar] = v.w;
    }
    {
      int bk = tid >> 4, bn = (tid & 15) * 4;
      *reinterpret_cast<float4*>(&Bs[bk][bn]) =
          *reinterpret_cast<const float4*>(&Wt[(size_t)(k0 + bk) * DM + n0 + bn]);
    }
    __syncthreads();
    #pragma unroll
    for (int kk = 0; kk < 16; ++kk) {
      float4 a4 = *reinterpret_cast<float4*>(&As[kk][tm * 4]);
      float4 b4 = *reinterpret_cast<float4*>(&Bs[kk][tn * 4]);
      acc[0][0] += a4.x * b4.x; acc[0][1] += a4.x * b4.y; acc[0][2] += a4.x * b4.z; acc[0][3] += a4.x * b4.w;
      acc[1][0] += a4.y * b4.x; acc[1][1] += a4.y * b4.y; acc[1][2] += a4.y * b4.z; acc[1][3] += a4.y * b4.w;
      acc[2][0] += a4.z * b4.x; acc[2][1] += a4.z * b4.y; acc[2][2] += a4.z * b4.z; acc[2][3] += a4.z * b4.w;
      acc[3][0] += a4.w * b4.x; acc[3][1] += a4.w * b4.y; acc[3][2] += a4.w * b4.z; acc[3][3] += a4.w * b4.w;
    }
    __syncthreads();
  }
  #pragma unroll
  for (int i = 0; i < 4; ++i)
    *reinterpret_cast<float4*>(&C[(size_t)(m0 + tm * 4 + i) * DM + n0 + tn * 4]) =
        make_float4(acc[i][0], acc[i][1], acc[i][2], acc[i][3]);
}

// ---------------------------------------------------------------------------
extern "C" void kernel_launch(void* const* d_in, const int* in_sizes, int n_in,
                              void* d_out, int out_size, void* d_ws, size_t ws_size,
                              hipStream_t stream) {
  const float* x      = (const float*)d_in[0];
  const float* query  = (const float*)d_in[1];
  const float* ln_q_w = (const float*)d_in[2];
  const float* ln_q_b = (const float*)d_in[3];
  const float* ln_k_w = (const float*)d_in[4];
  const float* ln_k_b = (const float*)d_in[5];
  const float* Wq     = (const float*)d_in[6];
  const float* Wkv    = (const float*)d_in[7];
  const float* Wout   = (const float*)d_in[8];
  float* out = (float*)d_out;

  float* qp            = (float*)d_ws;                        // 196608 f
  unsigned short* xn   = (unsigned short*)(qp + 196608);      // 33554432 bf16
  unsigned short* wkvT = xn + (size_t)MKV * CD;               // 1572864 bf16
  unsigned short* kvb  = wkvT + (size_t)NKV * CD;             // 50331648 bf16
  float* pO   = (float*)(kvb + (size_t)MKV * NKV);            // 3145728 f
  float* pM   = pO + (size_t)B_ * NH * 2 * NQ * DH;           // 49152 f
  float* pL   = pM + (size_t)B_ * NH * 2 * NQ;                // 49152 f
  float* attn = pL + (size_t)B_ * NH * 2 * NQ;                // 1572864 f

  hipLaunchKernelGGL(qproj_kernel, dim3(NQ), dim3(256), 0, stream,
                     query, ln_q_w, ln_q_b, Wq, qp);
  hipLaunchKernelGGL(xnorm_kernel, dim3(MKV), dim3(256), 0, stream,
                     x, ln_k_w, ln_k_b, xn);
  hipLaunchKernelGGL(wkvt_kernel, dim3(CD / 32, NKV / 32), dim3(256), 0, stream,
                     Wkv, wkvT);
  hipLaunchKernelGGL(kv_mfma_kernel, dim3((MKV / GBM) * (NKV / GBN)), dim3(256), 0, stream,
                     xn, wkvT, kvb);
  hipLaunchKernelGGL(attn_kernel, dim3(4, 2, B_ * NH), dim3(256), 0, stream,
                     qp, kvb, pO, pM, pL);
  hipLaunchKernelGGL(attn_combine_kernel, dim3(4, B_ * NH), dim3(256), 0, stream,
                     pO, pM, pL, attn);
  hipLaunchKernelGGL(out_gemm_kernel, dim3(2048 / 64, DM / 64), dim3(256), 0, stream,
                     attn, Wout, out);
}

// Round 5
// 364.618 us; speedup vs baseline: 5.7895x; 2.9394x over previous
//
#include <hip/hip_runtime.h>
#include <hip/hip_bf16.h>
#include <math.h>

#define B_    8
#define T_    4096
#define CD    1024
#define DM    768
#define NH    12
#define DH    64
#define NQ    256
#define INNER 768
#define NKV   1536
#define MKV   (B_*T_)
#define EPS   1e-5f
#define SCALE 0.125f

typedef __attribute__((ext_vector_type(8))) short short8;
typedef __attribute__((ext_vector_type(4))) float f32x4;

__device__ __forceinline__ unsigned short f2bf(float f) {
  union { __hip_bfloat16 h; unsigned short u; } cv;
  cv.h = __float2bfloat16(f);
  return cv.u;
}

// ---------------------------------------------------------------- q path ----
// One block per query row: LN over 768, then row @ Wq (768x768), scaled, bf16.
__global__ __launch_bounds__(256) void qproj_kernel(
    const float* __restrict__ query, const float* __restrict__ lnw,
    const float* __restrict__ lnb, const float* __restrict__ Wq,
    unsigned short* __restrict__ qpb) {
  int row = blockIdx.x, tid = threadIdx.x;
  __shared__ __attribute__((aligned(16))) float qn[DM];
  __shared__ float rbuf[256];
  const float* qr = query + (size_t)row * DM;
  float v0 = qr[tid], v1 = qr[tid + 256], v2 = qr[tid + 512];
  rbuf[tid] = v0 + v1 + v2;
  __syncthreads();
  for (int o = 128; o > 0; o >>= 1) { if (tid < o) rbuf[tid] += rbuf[tid + o]; __syncthreads(); }
  float mean = rbuf[0] * (1.f / 768.f);
  __syncthreads();
  float d0 = v0 - mean, d1 = v1 - mean, d2 = v2 - mean;
  rbuf[tid] = d0 * d0 + d1 * d1 + d2 * d2;
  __syncthreads();
  for (int o = 128; o > 0; o >>= 1) { if (tid < o) rbuf[tid] += rbuf[tid + o]; __syncthreads(); }
  float var = rbuf[0] * (1.f / 768.f);
  float rs = rsqrtf(var + EPS);
  qn[tid]       = d0 * rs * lnw[tid]       + lnb[tid];
  qn[tid + 256] = d1 * rs * lnw[tid + 256] + lnb[tid + 256];
  qn[tid + 512] = d2 * rs * lnw[tid + 512] + lnb[tid + 512];
  __syncthreads();
  float a0 = 0.f, a1 = 0.f, a2 = 0.f;
  for (int k = 0; k < DM; ++k) {
    float q = qn[k];
    const float* wr = Wq + (size_t)k * INNER;
    a0 += q * wr[tid];
    a1 += q * wr[tid + 256];
    a2 += q * wr[tid + 512];
  }
  unsigned short* dst = qpb + (size_t)row * INNER;
  dst[tid]       = f2bf(a0 * SCALE);
  dst[tid + 256] = f2bf(a1 * SCALE);
  dst[tid + 512] = f2bf(a2 * SCALE);
}

// ---------------------------- LN(x) -> bf16, fused stats + normalize -------
__global__ __launch_bounds__(256) void xnorm_kernel(
    const float* __restrict__ x, const float* __restrict__ lnw,
    const float* __restrict__ lnb, unsigned short* __restrict__ xn) {
  int row = blockIdx.x, tid = threadIdx.x;
  float4 v = reinterpret_cast<const float4*>(x + (size_t)row * CD)[tid];
  float s  = v.x + v.y + v.z + v.w;
  float ss = v.x * v.x + v.y * v.y + v.z * v.z + v.w * v.w;
  #pragma unroll
  for (int o = 32; o > 0; o >>= 1) { s += __shfl_down(s, o); ss += __shfl_down(ss, o); }
  __shared__ float sm[8];
  int wid = tid >> 6, lane = tid & 63;
  if (lane == 0) { sm[wid] = s; sm[4 + wid] = ss; }
  __syncthreads();
  float S  = sm[0] + sm[1] + sm[2] + sm[3];
  float SS = sm[4] + sm[5] + sm[6] + sm[7];
  float m  = S * (1.f / 1024.f);
  float var = SS * (1.f / 1024.f) - m * m;
  float rs = rsqrtf(fmaxf(var, 0.f) + EPS);
  float4 wv = reinterpret_cast<const float4*>(lnw)[tid];
  float4 bv = reinterpret_cast<const float4*>(lnb)[tid];
  ushort4 o4;
  o4.x = f2bf((v.x - m) * rs * wv.x + bv.x);
  o4.y = f2bf((v.y - m) * rs * wv.y + bv.y);
  o4.z = f2bf((v.z - m) * rs * wv.z + bv.z);
  o4.w = f2bf((v.w - m) * rs * wv.w + bv.w);
  reinterpret_cast<ushort4*>(xn + (size_t)row * CD)[tid] = o4;
}

// ---------------------- Wkv [1024][1536] -> WkvT bf16 [1536][1024] ---------
__global__ __launch_bounds__(256) void wkvt_kernel(
    const float* __restrict__ Wkv, unsigned short* __restrict__ wkvT) {
  __shared__ float tile[32][33];
  int k0 = blockIdx.x * 32, n0 = blockIdx.y * 32;
  int tid = threadIdx.x;
  int r = tid >> 3, c4 = (tid & 7) * 4;
  float4 v = *reinterpret_cast<const float4*>(&Wkv[(size_t)(k0 + r) * NKV + n0 + c4]);
  tile[r][c4 + 0] = v.x; tile[r][c4 + 1] = v.y; tile[r][c4 + 2] = v.z; tile[r][c4 + 3] = v.w;
  __syncthreads();
  ushort4 o4;
  o4.x = f2bf(tile[c4 + 0][r]);
  o4.y = f2bf(tile[c4 + 1][r]);
  o4.z = f2bf(tile[c4 + 2][r]);
  o4.w = f2bf(tile[c4 + 3][r]);
  *reinterpret_cast<ushort4*>(&wkvT[(size_t)(n0 + r) * CD + k0 + c4]) = o4;
}

// --------------------- kv = xn @ WkvT^T  (bf16 MFMA, fp32 acc) -------------
#define GBM 128
#define GBN 128
#define GBK 64
__global__ __launch_bounds__(256) void kv_mfma_kernel(
    const unsigned short* __restrict__ xn, const unsigned short* __restrict__ wkvT,
    unsigned short* __restrict__ kvb) {
  __shared__ __attribute__((aligned(16))) unsigned short As[GBM * GBK];
  __shared__ __attribute__((aligned(16))) unsigned short Bs[GBN * GBK];
  int tid = threadIdx.x;
  int w = tid >> 6, lane = tid & 63;

  int bid = blockIdx.x;
  int sw = (bid & 7) * (3072 / 8) + (bid >> 3);
  int mt = sw / (NKV / GBN), nt = sw % (NKV / GBN);
  int m0 = mt * GBM, n0 = nt * GBN;

  int srow[4], skoff[4];
  #pragma unroll
  for (int i = 0; i < 4; ++i) {
    int L = w * 4096 + i * 1024 + lane * 16;
    int row = L >> 7;
    int slot = (L >> 4) & 7;
    srow[i] = row;
    skoff[i] = ((slot ^ (row & 7)) << 3);
  }

  f32x4 acc[4][4];
  #pragma unroll
  for (int m = 0; m < 4; ++m)
    #pragma unroll
    for (int n = 0; n < 4; ++n) acc[m][n] = (f32x4){0.f, 0.f, 0.f, 0.f};

  int wr = w >> 1, wc = w & 1;
  int l15 = lane & 15, l4 = lane >> 4;

  for (int t = 0; t < CD / GBK; ++t) {
    int k0 = t * GBK;
    #pragma unroll
    for (int i = 0; i < 4; ++i) {
      __builtin_amdgcn_global_load_lds(
          (const __attribute__((address_space(1))) void*)(xn + (size_t)(m0 + srow[i]) * CD + k0 + skoff[i]),
          (__attribute__((address_space(3))) void*)(As + w * 2048 + i * 512 + lane * 8),
          16, 0, 0);
    }
    #pragma unroll
    for (int i = 0; i < 4; ++i) {
      __builtin_amdgcn_global_load_lds(
          (const __attribute__((address_space(1))) void*)(wkvT + (size_t)(n0 + srow[i]) * CD + k0 + skoff[i]),
          (__attribute__((address_space(3))) void*)(Bs + w * 2048 + i * 512 + lane * 8),
          16, 0, 0);
    }
    __syncthreads();
    #pragma unroll
    for (int kh = 0; kh < 2; ++kh) {
      short8 af[4], bf[4];
      #pragma unroll
      for (int m = 0; m < 4; ++m) {
        int row = wr * 64 + m * 16 + l15;
        int byte = row * 128 + (((l4 + 4 * kh) ^ (row & 7)) << 4);
        af[m] = *reinterpret_cast<const short8*>(reinterpret_cast<const char*>(As) + byte);
      }
      #pragma unroll
      for (int n = 0; n < 4; ++n) {
        int row = wc * 64 + n * 16 + l15;
        int byte = row * 128 + (((l4 + 4 * kh) ^ (row & 7)) << 4);
        bf[n] = *reinterpret_cast<const short8*>(reinterpret_cast<const char*>(Bs) + byte);
      }
      #pragma unroll
      for (int m = 0; m < 4; ++m)
        #pragma unroll
        for (int n = 0; n < 4; ++n)
          acc[m][n] = __builtin_amdgcn_mfma_f32_16x16x32_bf16(af[m], bf[n], acc[m][n], 0, 0, 0);
    }
    __syncthreads();
  }

  #pragma unroll
  for (int m = 0; m < 4; ++m) {
    int grow = m0 + wr * 64 + m * 16 + l4 * 4;
    #pragma unroll
    for (int n = 0; n < 4; ++n) {
      int gcol = n0 + wc * 64 + n * 16 + l15;
      #pragma unroll
      for (int r = 0; r < 4; ++r)
        kvb[(size_t)(grow + r) * NKV + gcol] = f2bf(acc[m][n][r]);
    }
  }
}

// ----------------- V transpose: kvb V-half -> vT[bh][64 d][4096 j] ---------
__global__ __launch_bounds__(256) void vtrans_kernel(
    const unsigned short* __restrict__ kvb, unsigned short* __restrict__ vT) {
  int jt = blockIdx.x, bh = blockIdx.y;
  int b = bh / NH, h = bh % NH;
  __shared__ __attribute__((aligned(16))) unsigned short t_[64][72];
  int tid = threadIdx.x;
  {
    int jr = tid >> 2, dp = (tid & 3) * 16;
    const unsigned short* src = kvb + (size_t)(b * T_ + jt * 64 + jr) * NKV + INNER + h * DH + dp;
    *reinterpret_cast<short8*>(&t_[jr][dp])     = *reinterpret_cast<const short8*>(src);
    *reinterpret_cast<short8*>(&t_[jr][dp + 8]) = *reinterpret_cast<const short8*>(src + 8);
  }
  __syncthreads();
  {
    int d = tid >> 2, jp = (tid & 3) * 16;
    unsigned short tmp[16];
    #pragma unroll
    for (int jj = 0; jj < 16; ++jj) tmp[jj] = t_[jp + jj][d];
    unsigned short* dst = vT + ((size_t)bh * DH + d) * T_ + jt * 64 + jp;
    *reinterpret_cast<short8*>(dst)     = *reinterpret_cast<const short8*>(&tmp[0]);
    *reinterpret_cast<short8*>(dst + 8) = *reinterpret_cast<const short8*>(&tmp[8]);
  }
}

// ------------------------- flash attention, bf16 MFMA ----------------------
// grid (4 qtiles, 2 kchunks, 96 bh); 4 waves, each owns 16 q rows.
// Swapped QK^T (S^T = mfma(K, Q)) -> per-lane q = lane&15 softmax;
// P through per-wave swizzled LDS; V^T staged from global vT.
__global__ __launch_bounds__(256) void attn_mfma_kernel(
    const unsigned short* __restrict__ qpb, const unsigned short* __restrict__ kvb,
    const unsigned short* __restrict__ vT,
    float* __restrict__ pO, float* __restrict__ pM, float* __restrict__ pL) {
  int qt = blockIdx.x, kc = blockIdx.y, bh = blockIdx.z;
  int b = bh / NH, h = bh % NH;
  __shared__ __attribute__((aligned(16))) unsigned short Ks[4096];
  __shared__ __attribute__((aligned(16))) unsigned short Vs[4096];
  __shared__ __attribute__((aligned(16))) unsigned short Ps[4][1024];
  int tid = threadIdx.x;
  int w = tid >> 6, lane = tid & 63;
  int l15 = lane & 15, l4 = lane >> 4;

  // Q fragments (B operand): lane holds q = w*16 + l15, d = hf*32 + l4*8
  short8 qf[2];
  {
    const unsigned short* qb = qpb + (size_t)(qt * 64 + w * 16 + l15) * INNER + h * DH;
    qf[0] = *reinterpret_cast<const short8*>(qb + l4 * 8);
    qf[1] = *reinterpret_cast<const short8*>(qb + 32 + l4 * 8);
  }

  // staging geometry: wave w covers rows w*16 .. w*16+15 of the 64-row tile
  int srow0 = w * 16 + (lane >> 3);
  int srow1 = srow0 + 8;
  int koff0 = (((lane & 7) ^ (srow0 & 7)) << 3);
  int koff1 = (((lane & 7) ^ (srow1 & 7)) << 3);

  f32x4 o[4];
  #pragma unroll
  for (int i = 0; i < 4; ++i) o[i] = (f32x4){0.f, 0.f, 0.f, 0.f};
  float m_run = -1e30f, l_run = 0.f;

  const size_t kbase = ((size_t)b * T_) * NKV + h * DH;
  const size_t vbase = ((size_t)bh * DH) * T_;

  for (int kt = 0; kt < 32; ++kt) {
    int j0 = kc * 2048 + kt * 64;
    __builtin_amdgcn_global_load_lds(
        (const __attribute__((address_space(1))) void*)(kvb + kbase + (size_t)(j0 + srow0) * NKV + koff0),
        (__attribute__((address_space(3))) void*)(Ks + w * 1024 + lane * 8), 16, 0, 0);
    __builtin_amdgcn_global_load_lds(
        (const __attribute__((address_space(1))) void*)(kvb + kbase + (size_t)(j0 + srow1) * NKV + koff1),
        (__attribute__((address_space(3))) void*)(Ks + w * 1024 + 512 + lane * 8), 16, 0, 0);
    __builtin_amdgcn_global_load_lds(
        (const __attribute__((address_space(1))) void*)(vT + vbase + (size_t)srow0 * T_ + j0 + koff0),
        (__attribute__((address_space(3))) void*)(Vs + w * 1024 + lane * 8), 16, 0, 0);
    __builtin_amdgcn_global_load_lds(
        (const __attribute__((address_space(1))) void*)(vT + vbase + (size_t)srow1 * T_ + j0 + koff1),
        (__attribute__((address_space(3))) void*)(Vs + w * 1024 + 512 + lane * 8), 16, 0, 0);
    __syncthreads();

    // S^T = K . Q^T : st[sub] holds keys sub*16 + l4*4 + r, q = l15
    f32x4 st[4];
    #pragma unroll
    for (int sub = 0; sub < 4; ++sub) {
      st[sub] = (f32x4){0.f, 0.f, 0.f, 0.f};
      #pragma unroll
      for (int hf = 0; hf < 2; ++hf) {
        int row = sub * 16 + l15;
        int byt = row * 128 + (((l4 + 4 * hf) ^ (row & 7)) << 4);
        short8 kf = *reinterpret_cast<const short8*>(reinterpret_cast<const char*>(Ks) + byt);
        st[sub] = __builtin_amdgcn_mfma_f32_16x16x32_bf16(kf, qf[hf], st[sub], 0, 0, 0);
      }
    }

    // online softmax over this 64-key tile (per q = l15, data replicated over l4 groups)
    float tmax = -1e30f;
    #pragma unroll
    for (int sub = 0; sub < 4; ++sub)
      #pragma unroll
      for (int r = 0; r < 4; ++r) tmax = fmaxf(tmax, st[sub][r]);
    tmax = fmaxf(tmax, __shfl_xor(tmax, 16));
    tmax = fmaxf(tmax, __shfl_xor(tmax, 32));
    float m_new = fmaxf(m_run, tmax);
    float alpha = __expf(m_run - m_new);
    float psum = 0.f;
    #pragma unroll
    for (int sub = 0; sub < 4; ++sub) {
      float p0 = __expf(st[sub][0] - m_new);
      float p1 = __expf(st[sub][1] - m_new);
      float p2 = __expf(st[sub][2] - m_new);
      float p3 = __expf(st[sub][3] - m_new);
      psum += (p0 + p1) + (p2 + p3);
      unsigned int u0 = (unsigned int)f2bf(p0) | ((unsigned int)f2bf(p1) << 16);
      unsigned int u1 = (unsigned int)f2bf(p2) | ((unsigned int)f2bf(p3) << 16);
      int slot = (sub * 2 + (l4 >> 1)) ^ (l15 & 7);
      int byt = l15 * 128 + (slot << 4) + (l4 & 1) * 8;
      uint2 uv; uv.x = u0; uv.y = u1;
      *reinterpret_cast<uint2*>(reinterpret_cast<char*>(Ps[w]) + byt) = uv;
    }
    psum += __shfl_xor(psum, 16);
    psum += __shfl_xor(psum, 32);
    l_run = l_run * alpha + psum;
    m_run = m_new;

    // rescale O (O rows q = l4*4 + r need alpha from lane (l4*4+r))
    float ao[4];
    #pragma unroll
    for (int r = 0; r < 4; ++r) ao[r] = __shfl(alpha, (l4 << 2) | r);
    #pragma unroll
    for (int ds = 0; ds < 4; ++ds)
      #pragma unroll
      for (int r = 0; r < 4; ++r) o[ds][r] *= ao[r];

    // O += P . V  (A = P from Ps[w], B = V^T rows from Vs)
    short8 pa[2];
    #pragma unroll
    for (int hf = 0; hf < 2; ++hf) {
      int byt = l15 * 128 + ((((hf << 2) + l4) ^ (l15 & 7)) << 4);
      pa[hf] = *reinterpret_cast<const short8*>(reinterpret_cast<const char*>(Ps[w]) + byt);
    }
    #pragma unroll
    for (int ds = 0; ds < 4; ++ds) {
      #pragma unroll
      for (int hf = 0; hf < 2; ++hf) {
        int row = ds * 16 + l15;
        int byt = row * 128 + (((l4 + 4 * hf) ^ (row & 7)) << 4);
        short8 vf = *reinterpret_cast<const short8*>(reinterpret_cast<const char*>(Vs) + byt);
        o[ds] = __builtin_amdgcn_mfma_f32_16x16x32_bf16(pa[hf], vf, o[ds], 0, 0, 0);
      }
    }
    __syncthreads();
  }

  int pidx = bh * 2 + kc;
  int qrow0 = qt * 64 + w * 16;
  if (l4 == 0) {
    pM[(size_t)pidx * NQ + qrow0 + l15] = m_run;
    pL[(size_t)pidx * NQ + qrow0 + l15] = l_run;
  }
  #pragma unroll
  for (int ds = 0; ds < 4; ++ds)
    #pragma unroll
    for (int r = 0; r < 4; ++r)
      pO[((size_t)pidx * NQ + qrow0 + l4 * 4 + r) * DH + ds * 16 + l15] = o[ds][r];
}

// ------------------------------------------------------- combine 2 chunks --
__global__ __launch_bounds__(256) void attn_combine_kernel(
    const float* __restrict__ pO, const float* __restrict__ pM,
    const float* __restrict__ pL, float* __restrict__ attn_out) {
  int qt = blockIdx.x, bh = blockIdx.y;
  int b = bh / NH, h = bh % NH;
  int tid = threadIdx.x;
  #pragma unroll
  for (int e = 0; e < 16; ++e) {
    int idx = e * 256 + tid;
    int r = idx >> 6, d = idx & 63;
    int row = qt * 64 + r;
    size_t i0 = (size_t)(bh * 2 + 0) * NQ + row;
    size_t i1 = (size_t)(bh * 2 + 1) * NQ + row;
    float m1 = pM[i0], m2 = pM[i1], l1 = pL[i0], l2 = pL[i1];
    float M = fmaxf(m1, m2);
    float w1 = __expf(m1 - M), w2 = __expf(m2 - M);
    float L = l1 * w1 + l2 * w2;
    float oo = (pO[i0 * DH + d] * w1 + pO[i1 * DH + d] * w2) / L;
    attn_out[((size_t)b * NQ + row) * INNER + h * DH + d] = oo;
  }
}

// --------------------------------------------------- out = attn @ Wout -----
__global__ __launch_bounds__(256) void out_gemm_kernel(
    const float* __restrict__ A, const float* __restrict__ Wt, float* __restrict__ C) {
  __shared__ __attribute__((aligned(16))) float As[16][68];
  __shared__ __attribute__((aligned(16))) float Bs[16][68];
  int m0 = blockIdx.x * 64, n0 = blockIdx.y * 64;
  int tid = threadIdx.x;
  int tm = tid >> 4, tn = tid & 15;
  float acc[4][4] = {};
  for (int k0 = 0; k0 < INNER; k0 += 16) {
    {
      int ar = tid >> 2, ak = (tid & 3) * 4;
      float4 v = *reinterpret_cast<const float4*>(&A[(size_t)(m0 + ar) * INNER + k0 + ak]);
      As[ak][ar] = v.x; As[ak + 1][ar] = v.y; As[ak + 2][ar] = v.z; As[ak + 3][ar] = v.w;
    }
    {
      int bk = tid >> 4, bn = (tid & 15) * 4;
      *reinterpret_cast<float4*>(&Bs[bk][bn]) =
          *reinterpret_cast<const float4*>(&Wt[(size_t)(k0 + bk) * DM + n0 + bn]);
    }
    __syncthreads();
    #pragma unroll
    for (int kk = 0; kk < 16; ++kk) {
      float4 a4 = *reinterpret_cast<float4*>(&As[kk][tm * 4]);
      float4 b4 = *reinterpret_cast<float4*>(&Bs[kk][tn * 4]);
      acc[0][0] += a4.x * b4.x; acc[0][1] += a4.x * b4.y; acc[0][2] += a4.x * b4.z; acc[0][3] += a4.x * b4.w;
      acc[1][0] += a4.y * b4.x; acc[1][1] += a4.y * b4.y; acc[1][2] += a4.y * b4.z; acc[1][3] += a4.y * b4.w;
      acc[2][0] += a4.z * b4.x; acc[2][1] += a4.z * b4.y; acc[2][2] += a4.z * b4.z; acc[2][3] += a4.z * b4.w;
      acc[3][0] += a4.w * b4.x; acc[3][1] += a4.w * b4.y; acc[3][2] += a4.w * b4.z; acc[3][3] += a4.w * b4.w;
    }
    __syncthreads();
  }
  #pragma unroll
  for (int i = 0; i < 4; ++i)
    *reinterpret_cast<float4*>(&C[(size_t)(m0 + tm * 4 + i) * DM + n0 + tn * 4]) =
        make_float4(acc[i][0], acc[i][1], acc[i][2], acc[i][3]);
}

// ---------------------------------------------------------------------------
extern "C" void kernel_launch(void* const* d_in, const int* in_sizes, int n_in,
                              void* d_out, int out_size, void* d_ws, size_t ws_size,
                              hipStream_t stream) {
  const float* x      = (const float*)d_in[0];
  const float* query  = (const float*)d_in[1];
  const float* ln_q_w = (const float*)d_in[2];
  const float* ln_q_b = (const float*)d_in[3];
  const float* ln_k_w = (const float*)d_in[4];
  const float* ln_k_b = (const float*)d_in[5];
  const float* Wq     = (const float*)d_in[6];
  const float* Wkv    = (const float*)d_in[7];
  const float* Wout   = (const float*)d_in[8];
  float* out = (float*)d_out;

  unsigned short* qpb  = (unsigned short*)d_ws;               // 196608 bf16
  unsigned short* xn   = qpb + (size_t)NQ * INNER;            // 33554432 bf16 (aliased by vT later)
  unsigned short* vT   = xn;                                  // 25165824 bf16 (after kv_mfma)
  unsigned short* wkvT = xn + (size_t)MKV * CD;               // 1572864 bf16
  unsigned short* kvb  = wkvT + (size_t)NKV * CD;             // 50331648 bf16
  float* pO   = (float*)(kvb + (size_t)MKV * NKV);            // 3145728 f
  float* pM   = pO + (size_t)B_ * NH * 2 * NQ * DH;           // 49152 f
  float* pL   = pM + (size_t)B_ * NH * 2 * NQ;                // 49152 f
  float* attn = pL + (size_t)B_ * NH * 2 * NQ;                // 1572864 f

  hipLaunchKernelGGL(qproj_kernel, dim3(NQ), dim3(256), 0, stream,
                     query, ln_q_w, ln_q_b, Wq, qpb);
  hipLaunchKernelGGL(xnorm_kernel, dim3(MKV), dim3(256), 0, stream,
                     x, ln_k_w, ln_k_b, xn);
  hipLaunchKernelGGL(wkvt_kernel, dim3(CD / 32, NKV / 32), dim3(256), 0, stream,
                     Wkv, wkvT);
  hipLaunchKernelGGL(kv_mfma_kernel, dim3((MKV / GBM) * (NKV / GBN)), dim3(256), 0, stream,
                     xn, wkvT, kvb);
  hipLaunchKernelGGL(vtrans_kernel, dim3(T_ / 64, B_ * NH), dim3(256), 0, stream,
                     kvb, vT);
  hipLaunchKernelGGL(attn_mfma_kernel, dim3(4, 2, B_ * NH), dim3(256), 0, stream,
                     qpb, kvb, vT, pO, pM, pL);
  hipLaunchKernelGGL(attn_combine_kernel, dim3(4, B_ * NH), dim3(256), 0, stream,
                     pO, pM, pL, attn);
  hipLaunchKernelGGL(out_gemm_kernel, dim3(2048 / 64, DM / 64), dim3(256), 0, stream,
                     attn, Wout, out);
}

// Round 7
// 284.792 us; speedup vs baseline: 7.4122x; 1.2803x over previous
//
#include <hip/hip_runtime.h>
#include <hip/hip_bf16.h>
#include <math.h>

#define B_    8
#define T_    4096
#define CD    1024
#define DM    768
#define NH    12
#define DH    64
#define NQ    256
#define INNER 768
#define NKV   1536
#define MKV   (B_*T_)
#define EPS   1e-5f
#define SCALE 0.125f

typedef __attribute__((ext_vector_type(8))) short short8;
typedef __attribute__((ext_vector_type(4))) float f32x4;

__device__ __forceinline__ unsigned short f2bf(float f) {
  union { __hip_bfloat16 h; unsigned short u; } cv;
  cv.h = __float2bfloat16(f);
  return cv.u;
}

// --------------------- generic f32 [R][Cn] -> bf16 [Cn][R] transpose -------
__global__ __launch_bounds__(256) void tb32_kernel(
    const float* __restrict__ src, unsigned short* __restrict__ dst,
    int Cn, int R) {
  __shared__ float tile[32][33];
  int k0 = blockIdx.x * 32, n0 = blockIdx.y * 32;
  int tid = threadIdx.x;
  int r = tid >> 3, c4 = (tid & 7) * 4;
  float4 v = *reinterpret_cast<const float4*>(&src[(size_t)(k0 + r) * Cn + n0 + c4]);
  tile[r][c4 + 0] = v.x; tile[r][c4 + 1] = v.y; tile[r][c4 + 2] = v.z; tile[r][c4 + 3] = v.w;
  __syncthreads();
  ushort4 o4;
  o4.x = f2bf(tile[c4 + 0][r]);
  o4.y = f2bf(tile[c4 + 1][r]);
  o4.z = f2bf(tile[c4 + 2][r]);
  o4.w = f2bf(tile[c4 + 3][r]);
  *reinterpret_cast<ushort4*>(&dst[(size_t)(n0 + r) * R + k0 + c4]) = o4;
}

// ----------------------------- LN(query) -> bf16 ---------------------------
__global__ __launch_bounds__(256) void qln_kernel(
    const float* __restrict__ query, const float* __restrict__ lnw,
    const float* __restrict__ lnb, unsigned short* __restrict__ qn) {
  int row = blockIdx.x, tid = threadIdx.x;
  __shared__ float rbuf[256];
  const float* qr = query + (size_t)row * DM;
  float v0 = qr[tid], v1 = qr[tid + 256], v2 = qr[tid + 512];
  rbuf[tid] = v0 + v1 + v2;
  __syncthreads();
  for (int o = 128; o > 0; o >>= 1) { if (tid < o) rbuf[tid] += rbuf[tid + o]; __syncthreads(); }
  float mean = rbuf[0] * (1.f / 768.f);
  __syncthreads();
  float d0 = v0 - mean, d1 = v1 - mean, d2 = v2 - mean;
  rbuf[tid] = d0 * d0 + d1 * d1 + d2 * d2;
  __syncthreads();
  for (int o = 128; o > 0; o >>= 1) { if (tid < o) rbuf[tid] += rbuf[tid + o]; __syncthreads(); }
  float var = rbuf[0] * (1.f / 768.f);
  float rs = rsqrtf(var + EPS);
  unsigned short* dst = qn + (size_t)row * DM;
  dst[tid]       = f2bf(d0 * rs * lnw[tid]       + lnb[tid]);
  dst[tid + 256] = f2bf(d1 * rs * lnw[tid + 256] + lnb[tid + 256]);
  dst[tid + 512] = f2bf(d2 * rs * lnw[tid + 512] + lnb[tid + 512]);
}

// ---------------------------- LN(x) -> bf16, fused stats + normalize -------
__global__ __launch_bounds__(256) void xnorm_kernel(
    const float* __restrict__ x, const float* __restrict__ lnw,
    const float* __restrict__ lnb, unsigned short* __restrict__ xn) {
  int row = blockIdx.x, tid = threadIdx.x;
  float4 v = reinterpret_cast<const float4*>(x + (size_t)row * CD)[tid];
  float s  = v.x + v.y + v.z + v.w;
  float ss = v.x * v.x + v.y * v.y + v.z * v.z + v.w * v.w;
  #pragma unroll
  for (int o = 32; o > 0; o >>= 1) { s += __shfl_down(s, o); ss += __shfl_down(ss, o); }
  __shared__ float sm[8];
  int wid = tid >> 6, lane = tid & 63;
  if (lane == 0) { sm[wid] = s; sm[4 + wid] = ss; }
  __syncthreads();
  float S  = sm[0] + sm[1] + sm[2] + sm[3];
  float SS = sm[4] + sm[5] + sm[6] + sm[7];
  float m  = S * (1.f / 1024.f);
  float var = SS * (1.f / 1024.f) - m * m;
  float rs = rsqrtf(fmaxf(var, 0.f) + EPS);
  float4 wv = reinterpret_cast<const float4*>(lnw)[tid];
  float4 bv = reinterpret_cast<const float4*>(lnb)[tid];
  ushort4 o4;
  o4.x = f2bf((v.x - m) * rs * wv.x + bv.x);
  o4.y = f2bf((v.y - m) * rs * wv.y + bv.y);
  o4.z = f2bf((v.z - m) * rs * wv.z + bv.z);
  o4.w = f2bf((v.w - m) * rs * wv.w + bv.w);
  reinterpret_cast<ushort4*>(xn + (size_t)row * CD)[tid] = o4;
}

// ----------- generic 128x128 bf16 MFMA GEMM: C = A[M][K] @ Bt[N][K]^T ------
// MODE 0: bf16 out with scale; MODE 1: f32 out.
template <int MODE>
__global__ __launch_bounds__(256) void gemm128_kernel(
    const unsigned short* __restrict__ A, const unsigned short* __restrict__ Bt,
    void* __restrict__ Cout, int N, int K, int nN, float scale, int swz) {
  __shared__ __attribute__((aligned(16))) unsigned short As[128 * 64];
  __shared__ __attribute__((aligned(16))) unsigned short Bs[128 * 64];
  int tid = threadIdx.x;
  int w = tid >> 6, lane = tid & 63;
  int bid = blockIdx.x;
  int sw = swz ? ((bid & 7) * ((int)gridDim.x >> 3) + (bid >> 3)) : bid;
  int mt = sw / nN, nt = sw % nN;
  int m0 = mt * 128, n0 = nt * 128;

  int srow[4], skoff[4];
  #pragma unroll
  for (int i = 0; i < 4; ++i) {
    int L = w * 4096 + i * 1024 + lane * 16;
    int row = L >> 7;
    int slot = (L >> 4) & 7;
    srow[i] = row;
    skoff[i] = ((slot ^ (row & 7)) << 3);
  }

  f32x4 acc[4][4];
  #pragma unroll
  for (int m = 0; m < 4; ++m)
    #pragma unroll
    for (int n = 0; n < 4; ++n) acc[m][n] = (f32x4){0.f, 0.f, 0.f, 0.f};

  int wr = w >> 1, wc = w & 1;
  int l15 = lane & 15, l4 = lane >> 4;

  for (int t = 0; t < K / 64; ++t) {
    int k0 = t * 64;
    #pragma unroll
    for (int i = 0; i < 4; ++i) {
      __builtin_amdgcn_global_load_lds(
          (const __attribute__((address_space(1))) void*)(A + (size_t)(m0 + srow[i]) * K + k0 + skoff[i]),
          (__attribute__((address_space(3))) void*)(As + w * 2048 + i * 512 + lane * 8),
          16, 0, 0);
    }
    #pragma unroll
    for (int i = 0; i < 4; ++i) {
      __builtin_amdgcn_global_load_lds(
          (const __attribute__((address_space(1))) void*)(Bt + (size_t)(n0 + srow[i]) * K + k0 + skoff[i]),
          (__attribute__((address_space(3))) void*)(Bs + w * 2048 + i * 512 + lane * 8),
          16, 0, 0);
    }
    __syncthreads();
    #pragma unroll
    for (int kh = 0; kh < 2; ++kh) {
      short8 af[4], bf[4];
      #pragma unroll
      for (int m = 0; m < 4; ++m) {
        int row = wr * 64 + m * 16 + l15;
        int byte = row * 128 + (((l4 + 4 * kh) ^ (row & 7)) << 4);
        af[m] = *reinterpret_cast<const short8*>(reinterpret_cast<const char*>(As) + byte);
      }
      #pragma unroll
      for (int n = 0; n < 4; ++n) {
        int row = wc * 64 + n * 16 + l15;
        int byte = row * 128 + (((l4 + 4 * kh) ^ (row & 7)) << 4);
        bf[n] = *reinterpret_cast<const short8*>(reinterpret_cast<const char*>(Bs) + byte);
      }
      #pragma unroll
      for (int m = 0; m < 4; ++m)
        #pragma unroll
        for (int n = 0; n < 4; ++n)
          acc[m][n] = __builtin_amdgcn_mfma_f32_16x16x32_bf16(af[m], bf[n], acc[m][n], 0, 0, 0);
    }
    __syncthreads();
  }

  #pragma unroll
  for (int m = 0; m < 4; ++m) {
    int grow = m0 + wr * 64 + m * 16 + l4 * 4;
    #pragma unroll
    for (int n = 0; n < 4; ++n) {
      int gcol = n0 + wc * 64 + n * 16 + l15;
      #pragma unroll
      for (int r = 0; r < 4; ++r) {
        if (MODE == 0)
          ((unsigned short*)Cout)[(size_t)(grow + r) * N + gcol] = f2bf(acc[m][n][r] * scale);
        else
          ((float*)Cout)[(size_t)(grow + r) * N + gcol] = acc[m][n][r];
      }
    }
  }
}

// ---------------- kv = xn @ wkvT^T : 256x256 tile, 8 waves, dbuf LDS -------
// Stage-early / drain-late pipeline: STAGE(t+1) issued before compute(t),
// one __syncthreads (vmcnt0+lgkm0+barrier) per K-tile.
#define KBM 256
#define KBN 256
#define KBK 64
__global__ __launch_bounds__(512, 2) void kv_mfma256_kernel(
    const unsigned short* __restrict__ xn, const unsigned short* __restrict__ wkvT,
    unsigned short* __restrict__ kvb) {
  __shared__ __attribute__((aligned(16))) unsigned short As[2][KBM * KBK];  // 64 KB
  __shared__ __attribute__((aligned(16))) unsigned short Bs[2][KBN * KBK];  // 64 KB
  int tid = threadIdx.x;
  int w = tid >> 6, lane = tid & 63;
  int wm = w >> 2, wn = w & 3;
  int l15 = lane & 15, l4 = lane >> 4;

  int bid = blockIdx.x;                      // 768 blocks, %8==0 -> bijective
  int sw = (bid & 7) * 96 + (bid >> 3);
  int mt = sw / (NKV / KBN), nt = sw % (NKV / KBN);
  int m0 = mt * KBM, n0 = nt * KBN;

  // staging: inst i covers LDS ushort [i*4096 + tid*8, +8)
  int srow[4], koff[4];
  #pragma unroll
  for (int i = 0; i < 4; ++i) {
    int r = i * 64 + (tid >> 3);
    srow[i] = r;
    koff[i] = (((tid & 7) ^ (r & 7)) << 3);
  }

  f32x4 acc[8][4];
  #pragma unroll
  for (int m = 0; m < 8; ++m)
    #pragma unroll
    for (int n = 0; n < 4; ++n) acc[m][n] = (f32x4){0.f, 0.f, 0.f, 0.f};

  // prologue: stage tile 0
  #pragma unroll
  for (int i = 0; i < 4; ++i) {
    __builtin_amdgcn_global_load_lds(
        (const __attribute__((address_space(1))) void*)(xn + (size_t)(m0 + srow[i]) * CD + koff[i]),
        (__attribute__((address_space(3))) void*)(&As[0][0] + i * 4096 + tid * 8), 16, 0, 0);
    __builtin_amdgcn_global_load_lds(
        (const __attribute__((address_space(1))) void*)(wkvT + (size_t)(n0 + srow[i]) * CD + koff[i]),
        (__attribute__((address_space(3))) void*)(&Bs[0][0] + i * 4096 + tid * 8), 16, 0, 0);
  }
  __syncthreads();

  for (int t = 0; t < CD / KBK; ++t) {
    int cur = t & 1;
    if (t + 1 < CD / KBK) {                      // stage next tile early
      int k0 = (t + 1) * KBK;
      #pragma unroll
      for (int i = 0; i < 4; ++i) {
        __builtin_amdgcn_global_load_lds(
            (const __attribute__((address_space(1))) void*)(xn + (size_t)(m0 + srow[i]) * CD + k0 + koff[i]),
            (__attribute__((address_space(3))) void*)(&As[cur ^ 1][0] + i * 4096 + tid * 8), 16, 0, 0);
        __builtin_amdgcn_global_load_lds(
            (const __attribute__((address_space(1))) void*)(wkvT + (size_t)(n0 + srow[i]) * CD + k0 + koff[i]),
            (__attribute__((address_space(3))) void*)(&Bs[cur ^ 1][0] + i * 4096 + tid * 8), 16, 0, 0);
      }
    }
    const char* Ab = reinterpret_cast<const char*>(&As[cur][0]);
    const char* Bb = reinterpret_cast<const char*>(&Bs[cur][0]);
    #pragma unroll
    for (int kh = 0; kh < 2; ++kh) {
      short8 bf[4];
      #pragma unroll
      for (int n = 0; n < 4; ++n) {
        int row = wn * 64 + n * 16 + l15;
        int byt = row * 128 + (((kh * 4 + l4) ^ (row & 7)) << 4);
        bf[n] = *reinterpret_cast<const short8*>(Bb + byt);
      }
      #pragma unroll
      for (int m = 0; m < 8; ++m) {
        int row = wm * 128 + m * 16 + l15;
        int byt = row * 128 + (((kh * 4 + l4) ^ (row & 7)) << 4);
        short8 af = *reinterpret_cast<const short8*>(Ab + byt);
        #pragma unroll
        for (int n = 0; n < 4; ++n)
          acc[m][n] = __builtin_amdgcn_mfma_f32_16x16x32_bf16(af, bf[n], acc[m][n], 0, 0, 0);
      }
    }
    __syncthreads();   // drains vmcnt(0): next tile staged; all reads of cur done
  }

  #pragma unroll
  for (int m = 0; m < 8; ++m) {
    int grow = m0 + wm * 128 + m * 16 + l4 * 4;
    #pragma unroll
    for (int n = 0; n < 4; ++n) {
      int gcol = n0 + wn * 64 + n * 16 + l15;
      #pragma unroll
      for (int r = 0; r < 4; ++r)
        kvb[(size_t)(grow + r) * NKV + gcol] = f2bf(acc[m][n][r]);
    }
  }
}

// ----------------- V transpose: kvb V-half -> vT[bh][64 d][4096 j] ---------
__global__ __launch_bounds__(256) void vtrans_kernel(
    const unsigned short* __restrict__ kvb, unsigned short* __restrict__ vT) {
  int jt = blockIdx.x, bh = blockIdx.y;
  int b = bh / NH, h = bh % NH;
  __shared__ __attribute__((aligned(16))) unsigned short t_[64][72];
  int tid = threadIdx.x;
  {
    int jr = tid >> 2, dp = (tid & 3) * 16;
    const unsigned short* src = kvb + (size_t)(b * T_ + jt * 64 + jr) * NKV + INNER + h * DH + dp;
    *reinterpret_cast<short8*>(&t_[jr][dp])     = *reinterpret_cast<const short8*>(src);
    *reinterpret_cast<short8*>(&t_[jr][dp + 8]) = *reinterpret_cast<const short8*>(src + 8);
  }
  __syncthreads();
  {
    int d = tid >> 2, jp = (tid & 3) * 16;
    unsigned short tmp[16];
    #pragma unroll
    for (int jj = 0; jj < 16; ++jj) tmp[jj] = t_[jp + jj][d];
    unsigned short* dst = vT + ((size_t)bh * DH + d) * T_ + jt * 64 + jp;
    *reinterpret_cast<short8*>(dst)     = *reinterpret_cast<const short8*>(&tmp[0]);
    *reinterpret_cast<short8*>(dst + 8) = *reinterpret_cast<const short8*>(&tmp[8]);
  }
}

// ------------------------- flash attention, bf16 MFMA ----------------------
__global__ __launch_bounds__(256) void attn_mfma_kernel(
    const unsigned short* __restrict__ qpb, const unsigned short* __restrict__ kvb,
    const unsigned short* __restrict__ vT,
    float* __restrict__ pO, float* __restrict__ pM, float* __restrict__ pL) {
  int qt = blockIdx.x, kc = blockIdx.y, bh = blockIdx.z;
  int b = bh / NH, h = bh % NH;
  __shared__ __attribute__((aligned(16))) unsigned short Ks[4096];
  __shared__ __attribute__((aligned(16))) unsigned short Vs[4096];
  __shared__ __attribute__((aligned(16))) unsigned short Ps[4][1024];
  int tid = threadIdx.x;
  int w = tid >> 6, lane = tid & 63;
  int l15 = lane & 15, l4 = lane >> 4;

  short8 qf[2];
  {
    const unsigned short* qb = qpb + (size_t)(qt * 64 + w * 16 + l15) * INNER + h * DH;
    qf[0] = *reinterpret_cast<const short8*>(qb + l4 * 8);
    qf[1] = *reinterpret_cast<const short8*>(qb + 32 + l4 * 8);
  }

  int srow0 = w * 16 + (lane >> 3);
  int srow1 = srow0 + 8;
  int koff0 = (((lane & 7) ^ (srow0 & 7)) << 3);
  int koff1 = (((lane & 7) ^ (srow1 & 7)) << 3);

  f32x4 o[4];
  #pragma unroll
  for (int i = 0; i < 4; ++i) o[i] = (f32x4){0.f, 0.f, 0.f, 0.f};
  float m_run = -1e30f, l_run = 0.f;

  const size_t kbase = ((size_t)b * T_) * NKV + h * DH;
  const size_t vbase = ((size_t)bh * DH) * T_;

  for (int kt = 0; kt < 32; ++kt) {
    int j0 = kc * 2048 + kt * 64;
    __builtin_amdgcn_global_load_lds(
        (const __attribute__((address_space(1))) void*)(kvb + kbase + (size_t)(j0 + srow0) * NKV + koff0),
        (__attribute__((address_space(3))) void*)(Ks + w * 1024 + lane * 8), 16, 0, 0);
    __builtin_amdgcn_global_load_lds(
        (const __attribute__((address_space(1))) void*)(kvb + kbase + (size_t)(j0 + srow1) * NKV + koff1),
        (__attribute__((address_space(3))) void*)(Ks + w * 1024 + 512 + lane * 8), 16, 0, 0);
    __builtin_amdgcn_global_load_lds(
        (const __attribute__((address_space(1))) void*)(vT + vbase + (size_t)srow0 * T_ + j0 + koff0),
        (__attribute__((address_space(3))) void*)(Vs + w * 1024 + lane * 8), 16, 0, 0);
    __builtin_amdgcn_global_load_lds(
        (const __attribute__((address_space(1))) void*)(vT + vbase + (size_t)srow1 * T_ + j0 + koff1),
        (__attribute__((address_space(3))) void*)(Vs + w * 1024 + 512 + lane * 8), 16, 0, 0);
    __syncthreads();

    f32x4 st[4];
    #pragma unroll
    for (int sub = 0; sub < 4; ++sub) {
      st[sub] = (f32x4){0.f, 0.f, 0.f, 0.f};
      #pragma unroll
      for (int hf = 0; hf < 2; ++hf) {
        int row = sub * 16 + l15;
        int byt = row * 128 + (((l4 + 4 * hf) ^ (row & 7)) << 4);
        short8 kf = *reinterpret_cast<const short8*>(reinterpret_cast<const char*>(Ks) + byt);
        st[sub] = __builtin_amdgcn_mfma_f32_16x16x32_bf16(kf, qf[hf], st[sub], 0, 0, 0);
      }
    }

    float tmax = -1e30f;
    #pragma unroll
    for (int sub = 0; sub < 4; ++sub)
      #pragma unroll
      for (int r = 0; r < 4; ++r) tmax = fmaxf(tmax, st[sub][r]);
    tmax = fmaxf(tmax, __shfl_xor(tmax, 16));
    tmax = fmaxf(tmax, __shfl_xor(tmax, 32));
    float m_new = fmaxf(m_run, tmax);
    float alpha = __expf(m_run - m_new);
    float psum = 0.f;
    #pragma unroll
    for (int sub = 0; sub < 4; ++sub) {
      float p0 = __expf(st[sub][0] - m_new);
      float p1 = __expf(st[sub][1] - m_new);
      float p2 = __expf(st[sub][2] - m_new);
      float p3 = __expf(st[sub][3] - m_new);
      psum += (p0 + p1) + (p2 + p3);
      unsigned int u0 = (unsigned int)f2bf(p0) | ((unsigned int)f2bf(p1) << 16);
      unsigned int u1 = (unsigned int)f2bf(p2) | ((unsigned int)f2bf(p3) << 16);
      int slot = (sub * 2 + (l4 >> 1)) ^ (l15 & 7);
      int byt = l15 * 128 + (slot << 4) + (l4 & 1) * 8;
      uint2 uv; uv.x = u0; uv.y = u1;
      *reinterpret_cast<uint2*>(reinterpret_cast<char*>(Ps[w]) + byt) = uv;
    }
    psum += __shfl_xor(psum, 16);
    psum += __shfl_xor(psum, 32);
    l_run = l_run * alpha + psum;
    m_run = m_new;

    float ao[4];
    #pragma unroll
    for (int r = 0; r < 4; ++r) ao[r] = __shfl(alpha, (l4 << 2) | r);
    #pragma unroll
    for (int ds = 0; ds < 4; ++ds)
      #pragma unroll
      for (int r = 0; r < 4; ++r) o[ds][r] *= ao[r];

    short8 pa[2];
    #pragma unroll
    for (int hf = 0; hf < 2; ++hf) {
      int byt = l15 * 128 + ((((hf << 2) + l4) ^ (l15 & 7)) << 4);
      pa[hf] = *reinterpret_cast<const short8*>(reinterpret_cast<const char*>(Ps[w]) + byt);
    }
    #pragma unroll
    for (int ds = 0; ds < 4; ++ds) {
      #pragma unroll
      for (int hf = 0; hf < 2; ++hf) {
        int row = ds * 16 + l15;
        int byt = row * 128 + (((l4 + 4 * hf) ^ (row & 7)) << 4);
        short8 vf = *reinterpret_cast<const short8*>(reinterpret_cast<const char*>(Vs) + byt);
        o[ds] = __builtin_amdgcn_mfma_f32_16x16x32_bf16(pa[hf], vf, o[ds], 0, 0, 0);
      }
    }
    __syncthreads();
  }

  int pidx = bh * 2 + kc;
  int qrow0 = qt * 64 + w * 16;
  if (l4 == 0) {
    pM[(size_t)pidx * NQ + qrow0 + l15] = m_run;
    pL[(size_t)pidx * NQ + qrow0 + l15] = l_run;
  }
  #pragma unroll
  for (int ds = 0; ds < 4; ++ds)
    #pragma unroll
    for (int r = 0; r < 4; ++r)
      pO[((size_t)pidx * NQ + qrow0 + l4 * 4 + r) * DH + ds * 16 + l15] = o[ds][r];
}

// ------------------------- combine 2 chunks -> bf16 ------------------------
__global__ __launch_bounds__(256) void attn_combine_kernel(
    const float* __restrict__ pO, const float* __restrict__ pM,
    const float* __restrict__ pL, unsigned short* __restrict__ attn_out) {
  int qt = blockIdx.x, bh = blockIdx.y;
  int b = bh / NH, h = bh % NH;
  int tid = threadIdx.x;
  #pragma unroll
  for (int e = 0; e < 16; ++e) {
    int idx = e * 256 + tid;
    int r = idx >> 6, d = idx & 63;
    int row = qt * 64 + r;
    size_t i0 = (size_t)(bh * 2 + 0) * NQ + row;
    size_t i1 = (size_t)(bh * 2 + 1) * NQ + row;
    float m1 = pM[i0], m2 = pM[i1], l1 = pL[i0], l2 = pL[i1];
    float M = fmaxf(m1, m2);
    float w1 = __expf(m1 - M), w2 = __expf(m2 - M);
    float L = l1 * w1 + l2 * w2;
    float oo = (pO[i0 * DH + d] * w1 + pO[i1 * DH + d] * w2) / L;
    attn_out[((size_t)b * NQ + row) * INNER + h * DH + d] = f2bf(oo);
  }
}

// ---------------------------------------------------------------------------
extern "C" void kernel_launch(void* const* d_in, const int* in_sizes, int n_in,
                              void* d_out, int out_size, void* d_ws, size_t ws_size,
                              hipStream_t stream) {
  const float* x      = (const float*)d_in[0];
  const float* query  = (const float*)d_in[1];
  const float* ln_q_w = (const float*)d_in[2];
  const float* ln_q_b = (const float*)d_in[3];
  const float* ln_k_w = (const float*)d_in[4];
  const float* ln_k_b = (const float*)d_in[5];
  const float* Wq     = (const float*)d_in[6];
  const float* Wkv    = (const float*)d_in[7];
  const float* Wout   = (const float*)d_in[8];
  float* out = (float*)d_out;

  unsigned short* qpb   = (unsigned short*)d_ws;              // 196608
  unsigned short* xn    = qpb + (size_t)NQ * INNER;           // 33554432
  unsigned short* vT    = xn;                                 // alias (after kv GEMM)
  unsigned short* wkvT  = xn + (size_t)MKV * CD;              // 1572864
  unsigned short* kvb   = wkvT + (size_t)NKV * CD;            // 50331648
  float* pO    = (float*)(kvb + (size_t)MKV * NKV);           // 3145728 f
  float* pM    = pO + (size_t)B_ * NH * 2 * NQ * DH;          // 49152 f
  float* pL    = pM + (size_t)B_ * NH * 2 * NQ;               // 49152 f
  unsigned short* attnb = (unsigned short*)(pL + (size_t)B_ * NH * 2 * NQ);  // 1572864
  unsigned short* qn    = attnb + (size_t)B_ * NQ * INNER;    // 196608
  unsigned short* WqT   = qn + (size_t)NQ * DM;               // 589824
  unsigned short* WoutT = WqT + (size_t)DM * INNER;           // 589824

  // weight transposes (bf16)
  hipLaunchKernelGGL(tb32_kernel, dim3(CD / 32, NKV / 32), dim3(256), 0, stream,
                     Wkv, wkvT, NKV, CD);
  hipLaunchKernelGGL(tb32_kernel, dim3(DM / 32, INNER / 32), dim3(256), 0, stream,
                     Wq, WqT, INNER, DM);
  hipLaunchKernelGGL(tb32_kernel, dim3(INNER / 32, DM / 32), dim3(256), 0, stream,
                     Wout, WoutT, DM, INNER);
  // q path: LN then MFMA GEMM (scaled, bf16 out)
  hipLaunchKernelGGL(qln_kernel, dim3(NQ), dim3(256), 0, stream,
                     query, ln_q_w, ln_q_b, qn);
  hipLaunchKernelGGL((gemm128_kernel<0>), dim3((NQ / 128) * (INNER / 128)), dim3(256), 0, stream,
                     qn, WqT, (void*)qpb, INNER, DM, INNER / 128, SCALE, 0);
  // kv path
  hipLaunchKernelGGL(xnorm_kernel, dim3(MKV), dim3(256), 0, stream,
                     x, ln_k_w, ln_k_b, xn);
  hipLaunchKernelGGL(kv_mfma256_kernel, dim3((MKV / KBM) * (NKV / KBN)), dim3(512), 0, stream,
                     xn, wkvT, kvb);
  hipLaunchKernelGGL(vtrans_kernel, dim3(T_ / 64, B_ * NH), dim3(256), 0, stream,
                     kvb, vT);
  // attention
  hipLaunchKernelGGL(attn_mfma_kernel, dim3(4, 2, B_ * NH), dim3(256), 0, stream,
                     qpb, kvb, vT, pO, pM, pL);
  hipLaunchKernelGGL(attn_combine_kernel, dim3(4, B_ * NH), dim3(256), 0, stream,
                     pO, pM, pL, attnb);
  // output projection (f32 out)
  hipLaunchKernelGGL((gemm128_kernel<1>), dim3((B_ * NQ / 128) * (DM / 128)), dim3(256), 0, stream,
                     attnb, WoutT, (void*)out, DM, INNER, DM / 128, 1.f, 1);
}